// Round 7
// baseline (3138.861 us; speedup 1.0000x reference)
//
#include <hip/hip_runtime.h>
#include <math.h>

// DGM edge sampler, N=8192, DIN=512, DEMB=256, K=16.
// Canonical-f32 pipeline (bit-faithful to the np reference): k-ascending FMA
// GEMMs, numpy-pairwise row sums, explicit __f*_rn at every op boundary.
// Round 7: 16-row blocks everywhere -> grid 512 (2 blocks/CU, 4 waves/SIMD),
// k_sel LDS ~54KB (Ha restaged per k-chunk), barrier drains overlap.

#define NN 8192
#define DI 512
#define DE 256
#define TK 16

typedef float4 f4;

// ======== K1/K2: C = [relu](Amat @ Bmat), Bmat is [KTOT][256] ========
// block: 16 rows x 256 cols, 512 threads; thread: 2 rows x 4 cols.
// A-reads wave-broadcast; B-reads stride-1 b128.
template <int KTOT, bool RELU>
__global__ __launch_bounds__(512, 4) void k_gemm2(const float* __restrict__ Amat, int lda,
                                                  const float* __restrict__ Bmat,
                                                  float* __restrict__ Cout) {
  __shared__ float As[16][36];   // 2.3 KB
  __shared__ float Bs[32][256];  // 32 KB
  const int i0 = blockIdx.x * 16;
  const int tid = threadIdx.x;
  const int rg = tid >> 6;   // 0..7 -> rows rg*2, rg*2+1
  const int cq = tid & 63;   // cols cq*4..+3
  const int r0 = rg * 2;
  float acc[2][4] = {};
  f4 pa;
  f4 pb[4];
  if (tid < 128) pa = *(const f4*)&Amat[(size_t)(i0 + (tid >> 3)) * lda + (tid & 7) * 4];
#pragma unroll
  for (int w = 0; w < 4; ++w) {
    const int lin = tid + 512 * w;
    pb[w] = *(const f4*)&Bmat[(size_t)(lin >> 6) * DE + (lin & 63) * 4];
  }

  for (int k0 = 0; k0 < KTOT; k0 += 32) {
    __syncthreads();
    if (tid < 128) *(f4*)&As[tid >> 3][(tid & 7) * 4] = pa;
#pragma unroll
    for (int w = 0; w < 4; ++w) {
      const int lin = tid + 512 * w;
      *(f4*)&Bs[lin >> 6][(lin & 63) * 4] = pb[w];
    }
    if (k0 + 32 < KTOT) {
      if (tid < 128)
        pa = *(const f4*)&Amat[(size_t)(i0 + (tid >> 3)) * lda + k0 + 32 + (tid & 7) * 4];
#pragma unroll
      for (int w = 0; w < 4; ++w) {
        const int lin = tid + 512 * w;
        pb[w] = *(const f4*)&Bmat[(size_t)(k0 + 32 + (lin >> 6)) * DE + (lin & 63) * 4];
      }
    }
    __syncthreads();
#pragma unroll
    for (int k4 = 0; k4 < 8; ++k4) {
      f4 av[2];
#pragma unroll
      for (int u = 0; u < 2; ++u) av[u] = *(const f4*)&As[r0 + u][k4 * 4];  // broadcast
#pragma unroll
      for (int kk = 0; kk < 4; ++kk) {  // k ascending
        f4 b = *(const f4*)&Bs[k4 * 4 + kk][cq * 4];  // stride-1 b128
        const float* bf = (const float*)&b;
#pragma unroll
        for (int u = 0; u < 2; ++u) {
          const float a = ((const float*)&av[u])[kk];
#pragma unroll
          for (int m = 0; m < 4; ++m) acc[u][m] = __fmaf_rn(a, bf[m], acc[u][m]);
        }
      }
    }
  }
#pragma unroll
  for (int u = 0; u < 2; ++u) {
    const int i = i0 + r0 + u;
    f4 o;
    float* of = (float*)&o;
#pragma unroll
    for (int m = 0; m < 4; ++m) of[m] = RELU ? fmaxf(acc[u][m], 0.0f) : acc[u][m];
    *(f4*)&Cout[(size_t)i * DE + cq * 4] = o;
  }
}

// ======== K2b: hbT[k][i] = hb[i][k]  (64x64 LDS tiles, pad 65) ========
__global__ __launch_bounds__(256) void k_tr(const float* __restrict__ hb,
                                            float* __restrict__ hbT) {
  __shared__ float t[64][65];
  const int i0 = blockIdx.x * 64;
  const int k0 = blockIdx.y * 64;
  const int tid = threadIdx.x;
#pragma unroll
  for (int l = 0; l < 4; ++l) {
    const int lin = tid + 256 * l;
    const int r = lin >> 4, cqq = lin & 15;
    f4 v = *(const f4*)&hb[(size_t)(i0 + r) * DE + k0 + cqq * 4];
    const float* vf = (const float*)&v;
#pragma unroll
    for (int w = 0; w < 4; ++w) t[r][cqq * 4 + w] = vf[w];
  }
  __syncthreads();
#pragma unroll
  for (int l = 0; l < 4; ++l) {
    const int kk = (tid >> 4) + 16 * l;
    const int iq = tid & 15;
    f4 o;
    float* of = (float*)&o;
#pragma unroll
    for (int w = 0; w < 4; ++w) of[w] = t[iq * 4 + w][kk];
    *(f4*)&hbT[(size_t)(k0 + kk) * NN + i0 + iq * 4] = o;
  }
}

// ======== K3: sq[i] = sum(h_i*h_i), numpy-pairwise structure ========
__global__ __launch_bounds__(256) void k_sq32(const float* __restrict__ hb,
                                              float* __restrict__ sq) {
  const int row = blockIdx.x * 256 + threadIdx.x;
  const float* h = hb + (size_t)row * DE;
  float half[2];
#pragma unroll
  for (int hx = 0; hx < 2; ++hx) {
    float p[8] = {};
    for (int t = 0; t < 16; ++t) {
      f4 v0 = *(const f4*)&h[hx * 128 + t * 8];
      f4 v1 = *(const f4*)&h[hx * 128 + t * 8 + 4];
      const float* v0f = (const float*)&v0;
      const float* v1f = (const float*)&v1;
#pragma unroll
      for (int m = 0; m < 4; ++m) {
        p[m] = __fadd_rn(p[m], __fmul_rn(v0f[m], v0f[m]));
        p[4 + m] = __fadd_rn(p[4 + m], __fmul_rn(v1f[m], v1f[m]));
      }
    }
    const float t01 = __fadd_rn(p[0], p[1]), t23 = __fadd_rn(p[2], p[3]);
    const float t45 = __fadd_rn(p[4], p[5]), t67 = __fadd_rn(p[6], p[7]);
    half[hx] = __fadd_rn(__fadd_rn(t01, t23), __fadd_rn(t45, t67));
  }
  sq[row] = __fadd_rn(half[0], half[1]);
}

// ======== K4: fused f32 scoring + parallel streaming top-16 ========
// block: 16 rows x j-tile 256, 512 threads, grid 512 (2 blocks/CU).
// compute thread: rg=tid>>6 (rows rg*2..+1, A broadcast), cq=tid&63 (4 cols).
// selector thread (tid<256): sr=tid>>4 row, ss=tid&15; register sorted top-16.
__global__ __launch_bounds__(512, 4) void k_sel(const float* __restrict__ hb,
                                                const float* __restrict__ hbT,
                                                const float* __restrict__ sqv,
                                                const float* __restrict__ q,
                                                const float* __restrict__ temp,
                                                float* __restrict__ out) {
  __shared__ float Has[16][36];  // 2.3 KB, restaged per 32-k chunk
  __shared__ float Bs[32][260];  // 33.3 KB (merge mv at end)
  __shared__ float sc[16][260];  // 16.6 KB (merge mj at end)
  __shared__ int curs[16][16];   // 1 KB
  const int i0 = blockIdx.x * 16;
  const int tid = threadIdx.x;
  const int rg = tid >> 6;  // 0..7
  const int cq = tid & 63;  // 0..63
  const int r0 = rg * 2;
  const int sr = tid >> 4;  // selector row (tid<256)
  const int ss = tid & 15;  // selector sub-index

  const float tt = fminf(fmaxf(temp[0], -5.0f), 5.0f);
  const float C = expf(tt);
  float sqi[2];
  sqi[0] = sqv[i0 + r0];
  sqi[1] = sqv[i0 + r0 + 1];

  float acc[2][4] = {};
  float lv[16];
  int lj[16];
#pragma unroll
  for (int u = 0; u < TK; ++u) { lv[u] = -3.0e38f; lj[u] = 0x7fffffff; }

  // prefetch chunk 0 (jt=0, kc=0)
  f4 pa;
  f4 pb[4];
  if (tid < 128) pa = *(const f4*)&hb[(size_t)(i0 + (tid >> 3)) * DE + (tid & 7) * 4];
#pragma unroll
  for (int w = 0; w < 4; ++w) {
    const int lin = tid + 512 * w;
    pb[w] = *(const f4*)&hbT[(size_t)(lin >> 6) * NN + (lin & 63) * 4];
  }

  for (int s = 0; s < 256; ++s) {  // jt = s>>3, kc = s&7
    __syncthreads();               // Has/Bs free
    if (tid < 128) *(f4*)&Has[tid >> 3][(tid & 7) * 4] = pa;
#pragma unroll
    for (int w = 0; w < 4; ++w) {
      const int lin = tid + 512 * w;
      *(f4*)&Bs[lin >> 6][(lin & 63) * 4] = pb[w];
    }
    if (s + 1 < 256) {
      const int jt1 = (s + 1) >> 3, kc1 = (s + 1) & 7;
      if (tid < 128)
        pa = *(const f4*)&hb[(size_t)(i0 + (tid >> 3)) * DE + kc1 * 32 + (tid & 7) * 4];
#pragma unroll
      for (int w = 0; w < 4; ++w) {
        const int lin = tid + 512 * w;
        pb[w] = *(const f4*)&hbT[(size_t)(kc1 * 32 + (lin >> 6)) * NN + jt1 * 256 + (lin & 63) * 4];
      }
    }
    __syncthreads();               // staged tiles ready
#pragma unroll
    for (int k4 = 0; k4 < 8; ++k4) {
      f4 av[2];
#pragma unroll
      for (int u = 0; u < 2; ++u) av[u] = *(const f4*)&Has[r0 + u][k4 * 4];  // broadcast
#pragma unroll
      for (int kk = 0; kk < 4; ++kk) {  // k ascending
        f4 b = *(const f4*)&Bs[k4 * 4 + kk][cq * 4];  // stride-1 b128
        const float* bf = (const float*)&b;
#pragma unroll
        for (int u = 0; u < 2; ++u) {
          const float a = ((const float*)&av[u])[kk];
#pragma unroll
          for (int m = 0; m < 4; ++m) acc[u][m] = __fmaf_rn(a, bf[m], acc[u][m]);
        }
      }
    }
    if ((s & 7) == 7) {
      const int j0s = (s >> 3) * 256;
      // scores (instruction-identical to the round-4 passing formula)
      f4 sqj = *(const f4*)&sqv[j0s + cq * 4];
      const float* sqjf = (const float*)&sqj;
#pragma unroll
      for (int u = 0; u < 2; ++u) {
        const int i = i0 + r0 + u;
        f4 qv = *(const f4*)&q[(size_t)i * NN + j0s + cq * 4];
        const float* qvf = (const float*)&qv;
        f4 sv;
        float* svf = (float*)&sv;
#pragma unroll
        for (int e = 0; e < 4; ++e) {
          const float t1 = __fadd_rn(sqi[u], sqjf[e]);
          float D = __fsub_rn(t1, __fmul_rn(2.0f, acc[u][e]));
          D = fmaxf(D, 0.0f);
          const float lg = __fmul_rn(D, C);
          const float p = __fadd_rn(qvf[e], 1e-8f);
          const float uu = logf(p);
          const float nv = logf(-uu);
          svf[e] = __fsub_rn(nv, lg);
          acc[u][e] = 0.0f;
        }
        *(f4*)&sc[r0 + u][cq * 4] = sv;
      }
      __syncthreads();             // sc ready
      // selection (tid<256): ascending j (j = j0s + c*16 + ss)
      if (tid < 256) {
        for (int c = 0; c < 16; ++c) {
          const float v = sc[sr][c * 16 + ss];
          if (v > lv[15]) {        // strict: ties keep earlier (smaller) j
            float cv = v;
            int cj = j0s + c * 16 + ss;
#pragma unroll
            for (int u = 0; u < TK; ++u) {
              const bool take = (cv > lv[u]);
              const float nv2 = take ? cv : lv[u];
              const int nj2 = take ? cj : lj[u];
              cv = take ? lv[u] : cv;
              cj = take ? lj[u] : cj;
              lv[u] = nv2;
              lj[u] = nj2;
            }
          }
        }
      }
      // next iteration's first barrier protects sc/Bs reuse
    }
  }

  // ---- merge: dump sorted lists, 16-way sorted merge per row ----
  __syncthreads();
  float* mv = &Bs[0][0];      // 256*16 floats = 16 KB
  int* mj = (int*)&sc[0][0];  // 256*16 ints
  if (tid < 256) {
#pragma unroll
    for (int u = 0; u < TK; ++u) {
      mv[tid * TK + u] = lv[u];
      mj[tid * TK + u] = lj[u];
    }
  }
  __syncthreads();
  if (tid < 16) {
    const int r = tid;
    for (int s2 = 0; s2 < 16; ++s2) curs[r][s2] = 0;
    float* E0 = out + (size_t)NN * DE;
    float* E1 = E0 + (size_t)NN * TK;
    float* LP = E1 + (size_t)NN * TK;
    for (int it = 0; it < TK; ++it) {
      float bvv = -3.0e38f;
      int bj = 0x7fffffff, bs = 0;
      for (int s2 = 0; s2 < 16; ++s2) {
        const int cu = curs[r][s2];
        if (cu < TK) {
          const float v = mv[(r * 16 + s2) * TK + cu];
          const int jx = mj[(r * 16 + s2) * TK + cu];
          if (v > bvv || (v == bvv && jx < bj)) { bvv = v; bj = jx; bs = s2; }
        }
      }
      curs[r][bs]++;
      E0[(size_t)(i0 + r) * TK + it] = (float)bj;
      E1[(size_t)(i0 + r) * TK + it] = (float)(i0 + r);
      LP[(size_t)(i0 + r) * TK + it] = bvv;
    }
  }
}

extern "C" void kernel_launch(void* const* d_in, const int* in_sizes, int n_in,
                              void* d_out, int out_size, void* d_ws, size_t ws_size,
                              hipStream_t stream) {
  const float* x = (const float*)d_in[0];
  const float* A = (const float*)d_in[1];
  const float* W = (const float*)d_in[2];
  const float* temp = (const float*)d_in[3];
  const float* q = (const float*)d_in[4];
  float* out = (float*)d_out;

  char* ws = (char*)d_ws;
  float* xw = (float*)(ws);             //  8,388,608 B
  float* sq = (float*)(ws + 8388608);   //     32,768 B
  float* hbT = (float*)(ws + 8421376);  //  8,388,608 B  [256][8192]

  float* hb = out;  // [N, DE] f32 output region holds h

  hipLaunchKernelGGL((k_gemm2<DI, false>), dim3(NN / 16), dim3(512), 0, stream, x, DI, W, xw);
  hipLaunchKernelGGL((k_gemm2<NN, true>), dim3(NN / 16), dim3(512), 0, stream, A, NN, xw, hb);
  hipLaunchKernelGGL(k_tr, dim3(NN / 64, DE / 64), dim3(256), 0, stream, hb, hbT);
  hipLaunchKernelGGL(k_sq32, dim3(NN / 256), dim3(256), 0, stream, hb, sq);
  hipLaunchKernelGGL(k_sel, dim3(NN / 16), dim3(512), 0, stream, hb, hbT, sq, q, temp, out);
}

// Round 8
// 2313.455 us; speedup vs baseline: 1.3568x; 1.3568x over previous
//
#include <hip/hip_runtime.h>
#include <math.h>

// DGM edge sampler, N=8192, DIN=512, DEMB=256, K=16.
// Canonical-f32 pipeline (bit-faithful to the np reference): k-ascending FMA
// GEMMs, numpy-pairwise row sums, explicit __f*_rn at every op boundary.
// Round 8: k_sel split over j (grid 256x2, 2 blocks/CU, LDS 73KB, no reg cap;
// round-7 lesson: launch_bounds(,4) caused VGPR=64 -> 3.4GB scratch spills).
// Per-block per-row top-16 -> workspace; k_merge folds the two j-halves.

#define NN 8192
#define DI 512
#define DE 256
#define TK 16

typedef float4 f4;

// ======== K1/K2: C = [relu](Amat @ Bmat), Bmat is [KTOT][256] ========
// (round-6 proven version: 32 rows x 256 cols, 512 threads)
template <int KTOT, bool RELU>
__global__ __launch_bounds__(512) void k_gemm(const float* __restrict__ Amat, int lda,
                                              const float* __restrict__ Bmat,
                                              float* __restrict__ Cout) {
  __shared__ float As[32][32];   // 4 KB
  __shared__ float Bs[32][256];  // 32 KB
  const int i0 = blockIdx.x * 32;
  const int tid = threadIdx.x;
  const int g = tid >> 5;
  const int cg = tid & 31;
  const int arow = tid >> 3, aq = tid & 7;
  const int bkk = tid >> 4, bq = tid & 15;
  float acc[2][8] = {};
  f4 pa;
  f4 pb[4];
  if (tid < 256) pa = *(const f4*)&Amat[(size_t)(i0 + arow) * lda + aq * 4];
#pragma unroll
  for (int l = 0; l < 4; ++l)
    pb[l] = *(const f4*)&Bmat[(size_t)bkk * DE + (bq + 16 * l) * 4];

  for (int k0 = 0; k0 < KTOT; k0 += 32) {
    __syncthreads();
    if (tid < 256) *(f4*)&As[arow][aq * 4] = pa;
#pragma unroll
    for (int l = 0; l < 4; ++l) *(f4*)&Bs[bkk][(bq + 16 * l) * 4] = pb[l];
    if (k0 + 32 < KTOT) {
      if (tid < 256) pa = *(const f4*)&Amat[(size_t)(i0 + arow) * lda + k0 + 32 + aq * 4];
#pragma unroll
      for (int l = 0; l < 4; ++l)
        pb[l] = *(const f4*)&Bmat[(size_t)(k0 + 32 + bkk) * DE + (bq + 16 * l) * 4];
    }
    __syncthreads();
#pragma unroll
    for (int k4 = 0; k4 < 8; ++k4) {
      f4 a0 = *(const f4*)&As[g * 2 + 0][k4 * 4];
      f4 a1 = *(const f4*)&As[g * 2 + 1][k4 * 4];
      const float* a0f = (const float*)&a0;
      const float* a1f = (const float*)&a1;
#pragma unroll
      for (int qq = 0; qq < 4; ++qq) {
        f4 b0 = *(const f4*)&Bs[k4 * 4 + qq][cg * 4];
        f4 b1 = *(const f4*)&Bs[k4 * 4 + qq][128 + cg * 4];
        const float* b0f = (const float*)&b0;
        const float* b1f = (const float*)&b1;
#pragma unroll
        for (int m = 0; m < 4; ++m) {
          acc[0][m] = __fmaf_rn(a0f[qq], b0f[m], acc[0][m]);
          acc[1][m] = __fmaf_rn(a1f[qq], b0f[m], acc[1][m]);
          acc[0][4 + m] = __fmaf_rn(a0f[qq], b1f[m], acc[0][4 + m]);
          acc[1][4 + m] = __fmaf_rn(a1f[qq], b1f[m], acc[1][4 + m]);
        }
      }
    }
  }
#pragma unroll
  for (int u = 0; u < 2; ++u) {
    const int i = i0 + g * 2 + u;
    f4 o0, o1;
    float* o0f = (float*)&o0;
    float* o1f = (float*)&o1;
#pragma unroll
    for (int m = 0; m < 4; ++m) {
      o0f[m] = RELU ? fmaxf(acc[u][m], 0.0f) : acc[u][m];
      o1f[m] = RELU ? fmaxf(acc[u][4 + m], 0.0f) : acc[u][4 + m];
    }
    *(f4*)&Cout[(size_t)i * DE + cg * 4] = o0;
    *(f4*)&Cout[(size_t)i * DE + 128 + cg * 4] = o1;
  }
}

// ======== K2b: hbT[k][i] = hb[i][k]  (64x64 LDS tiles, pad 65) ========
__global__ __launch_bounds__(256) void k_tr(const float* __restrict__ hb,
                                            float* __restrict__ hbT) {
  __shared__ float t[64][65];
  const int i0 = blockIdx.x * 64;
  const int k0 = blockIdx.y * 64;
  const int tid = threadIdx.x;
#pragma unroll
  for (int l = 0; l < 4; ++l) {
    const int lin = tid + 256 * l;
    const int r = lin >> 4, cqq = lin & 15;
    f4 v = *(const f4*)&hb[(size_t)(i0 + r) * DE + k0 + cqq * 4];
    const float* vf = (const float*)&v;
#pragma unroll
    for (int w = 0; w < 4; ++w) t[r][cqq * 4 + w] = vf[w];
  }
  __syncthreads();
#pragma unroll
  for (int l = 0; l < 4; ++l) {
    const int kk = (tid >> 4) + 16 * l;
    const int iq = tid & 15;
    f4 o;
    float* of = (float*)&o;
#pragma unroll
    for (int w = 0; w < 4; ++w) of[w] = t[iq * 4 + w][kk];
    *(f4*)&hbT[(size_t)(k0 + kk) * NN + i0 + iq * 4] = o;
  }
}

// ======== K3: sq[i] = sum(h_i*h_i), numpy-pairwise structure ========
__global__ __launch_bounds__(256) void k_sq32(const float* __restrict__ hb,
                                              float* __restrict__ sq) {
  const int row = blockIdx.x * 256 + threadIdx.x;
  const float* h = hb + (size_t)row * DE;
  float half[2];
#pragma unroll
  for (int hx = 0; hx < 2; ++hx) {
    float p[8] = {};
    for (int t = 0; t < 16; ++t) {
      f4 v0 = *(const f4*)&h[hx * 128 + t * 8];
      f4 v1 = *(const f4*)&h[hx * 128 + t * 8 + 4];
      const float* v0f = (const float*)&v0;
      const float* v1f = (const float*)&v1;
#pragma unroll
      for (int m = 0; m < 4; ++m) {
        p[m] = __fadd_rn(p[m], __fmul_rn(v0f[m], v0f[m]));
        p[4 + m] = __fadd_rn(p[4 + m], __fmul_rn(v1f[m], v1f[m]));
      }
    }
    const float t01 = __fadd_rn(p[0], p[1]), t23 = __fadd_rn(p[2], p[3]);
    const float t45 = __fadd_rn(p[4], p[5]), t67 = __fadd_rn(p[6], p[7]);
    half[hx] = __fadd_rn(__fadd_rn(t01, t23), __fadd_rn(t45, t67));
  }
  sq[row] = __fadd_rn(half[0], half[1]);
}

// ======== K4: fused f32 scoring + parallel streaming top-16 (j-split) ========
// grid (NN/32, 2): 32 rows x 4096-j half per block, 512 threads, 2 blocks/CU.
// compute thread: rg=tid>>6 (rows rg*4..+3, A broadcast), cq=tid&63 (4 cols).
// selector thread: sr=tid>>4 row, ss=tid&15; register sorted top-16.
// Emits per-(row, j-half) top-16 to wsV/wsJ; k_merge folds halves.
__global__ __launch_bounds__(512) void k_sel(const float* __restrict__ hb,
                                             const float* __restrict__ hbT,
                                             const float* __restrict__ sqv,
                                             const float* __restrict__ q,
                                             const float* __restrict__ temp,
                                             float* __restrict__ wsV,
                                             int* __restrict__ wsJ) {
  __shared__ float Has[32][36];  // 4.6 KB, restaged per 32-k chunk
  __shared__ float Bs[32][260];  // 33.3 KB (merge mv at end)
  __shared__ float sc[32][260];  // 33.3 KB (merge mj at end)
  __shared__ int curs[32][16];   // 2 KB
  const int i0 = blockIdx.x * 32;
  const int jb = blockIdx.y;        // j-half: [jb*4096, jb*4096+4096)
  const int jbase = jb * 4096;
  const int tid = threadIdx.x;
  const int rg = tid >> 6;  // 0..7
  const int cq = tid & 63;  // 0..63
  const int r0 = rg * 4;
  const int sr = tid >> 4;  // selector row 0..31
  const int ss = tid & 15;  // selector sub-index

  const float tt = fminf(fmaxf(temp[0], -5.0f), 5.0f);
  const float C = expf(tt);
  float sqi[4];
#pragma unroll
  for (int u = 0; u < 4; ++u) sqi[u] = sqv[i0 + r0 + u];

  float acc[4][4] = {};
  float lv[16];
  int lj[16];
#pragma unroll
  for (int u = 0; u < TK; ++u) { lv[u] = -3.0e38f; lj[u] = 0x7fffffff; }

  // prefetch chunk 0 (jt=0, kc=0)
  f4 pa;
  f4 pb[4];
  if (tid < 256) pa = *(const f4*)&hb[(size_t)(i0 + (tid >> 3)) * DE + (tid & 7) * 4];
#pragma unroll
  for (int w = 0; w < 4; ++w) {
    const int lin = tid + 512 * w;
    pb[w] = *(const f4*)&hbT[(size_t)(lin >> 6) * NN + jbase + (lin & 63) * 4];
  }

  for (int s = 0; s < 128; ++s) {  // jt = s>>3 (16 tiles), kc = s&7
    __syncthreads();               // Has/Bs free
    if (tid < 256) *(f4*)&Has[tid >> 3][(tid & 7) * 4] = pa;
#pragma unroll
    for (int w = 0; w < 4; ++w) {
      const int lin = tid + 512 * w;
      *(f4*)&Bs[lin >> 6][(lin & 63) * 4] = pb[w];
    }
    if (s + 1 < 128) {
      const int jt1 = (s + 1) >> 3, kc1 = (s + 1) & 7;
      if (tid < 256)
        pa = *(const f4*)&hb[(size_t)(i0 + (tid >> 3)) * DE + kc1 * 32 + (tid & 7) * 4];
#pragma unroll
      for (int w = 0; w < 4; ++w) {
        const int lin = tid + 512 * w;
        pb[w] = *(const f4*)&hbT[(size_t)(kc1 * 32 + (lin >> 6)) * NN + jbase + jt1 * 256 + (lin & 63) * 4];
      }
    }
    __syncthreads();               // staged tiles ready
#pragma unroll
    for (int k4 = 0; k4 < 8; ++k4) {
      f4 av[4];
#pragma unroll
      for (int u = 0; u < 4; ++u) av[u] = *(const f4*)&Has[r0 + u][k4 * 4];  // broadcast
#pragma unroll
      for (int kk = 0; kk < 4; ++kk) {  // k ascending
        f4 b = *(const f4*)&Bs[k4 * 4 + kk][cq * 4];  // stride-1 b128
        const float* bf = (const float*)&b;
#pragma unroll
        for (int u = 0; u < 4; ++u) {
          const float a = ((const float*)&av[u])[kk];
#pragma unroll
          for (int m = 0; m < 4; ++m) acc[u][m] = __fmaf_rn(a, bf[m], acc[u][m]);
        }
      }
    }
    if ((s & 7) == 7) {
      const int j0s = jbase + (s >> 3) * 256;
      // scores (instruction-identical to the round-4 passing formula)
      f4 sqj = *(const f4*)&sqv[j0s + cq * 4];
      const float* sqjf = (const float*)&sqj;
#pragma unroll
      for (int u = 0; u < 4; ++u) {
        const int i = i0 + r0 + u;
        f4 qv = *(const f4*)&q[(size_t)i * NN + j0s + cq * 4];
        const float* qvf = (const float*)&qv;
        f4 sv;
        float* svf = (float*)&sv;
#pragma unroll
        for (int e = 0; e < 4; ++e) {
          const float t1 = __fadd_rn(sqi[u], sqjf[e]);
          float D = __fsub_rn(t1, __fmul_rn(2.0f, acc[u][e]));
          D = fmaxf(D, 0.0f);
          const float lg = __fmul_rn(D, C);
          const float p = __fadd_rn(qvf[e], 1e-8f);
          const float uu = logf(p);
          const float nv = logf(-uu);
          svf[e] = __fsub_rn(nv, lg);
          acc[u][e] = 0.0f;
        }
        *(f4*)&sc[r0 + u][cq * 4] = sv;
      }
      __syncthreads();             // sc ready
      // selection: ascending j within selector (j = j0s + c*16 + ss)
      for (int c = 0; c < 16; ++c) {
        const float v = sc[sr][c * 16 + ss];
        if (v > lv[15]) {          // strict: ties keep earlier (smaller) j
          float cv = v;
          int cj = j0s + c * 16 + ss;
#pragma unroll
          for (int u = 0; u < TK; ++u) {
            const bool take = (cv > lv[u]);
            const float nv2 = take ? cv : lv[u];
            const int nj2 = take ? cj : lj[u];
            cv = take ? lv[u] : cv;
            cj = take ? lj[u] : cj;
            lv[u] = nv2;
            lj[u] = nj2;
          }
        }
      }
      // next iteration's first barrier protects sc/Bs reuse
    }
  }

  // ---- in-block merge: 16 sorted lists per row -> top-16 -> workspace ----
  __syncthreads();
  float* mv = &Bs[0][0];      // 512*16 floats = 32 KB
  int* mj = (int*)&sc[0][0];  // 512*16 ints
#pragma unroll
  for (int u = 0; u < TK; ++u) {
    mv[tid * TK + u] = lv[u];
    mj[tid * TK + u] = lj[u];
  }
  __syncthreads();
  if (tid < 32) {
    const int r = tid;
    for (int s2 = 0; s2 < 16; ++s2) curs[r][s2] = 0;
    for (int it = 0; it < TK; ++it) {
      float bvv = -3.0e38f;
      int bj = 0x7fffffff, bs = 0;
      for (int s2 = 0; s2 < 16; ++s2) {
        const int cu = curs[r][s2];
        if (cu < TK) {
          const float v = mv[(r * 16 + s2) * TK + cu];
          const int jx = mj[(r * 16 + s2) * TK + cu];
          if (v > bvv || (v == bvv && jx < bj)) { bvv = v; bj = jx; bs = s2; }
        }
      }
      curs[r][bs]++;
      const size_t o = ((size_t)jb * NN + i0 + r) * TK + it;
      wsV[o] = bvv;
      wsJ[o] = bj;
    }
  }
}

// ======== K5: merge the two j-half top-16 lists per row ========
// Lists are sorted desc; jb=0 indices < jb=1 indices, so ties prefer a.
__global__ __launch_bounds__(256) void k_merge(const float* __restrict__ wsV,
                                               const int* __restrict__ wsJ,
                                               float* __restrict__ out) {
  const int r = blockIdx.x * 256 + threadIdx.x;
  const float* va = wsV + (size_t)r * TK;
  const int* ja = wsJ + (size_t)r * TK;
  const float* vb = wsV + ((size_t)NN + r) * TK;
  const int* jb_ = wsJ + ((size_t)NN + r) * TK;
  float* E0 = out + (size_t)NN * DE;
  float* E1 = E0 + (size_t)NN * TK;
  float* LP = E1 + (size_t)NN * TK;
  int ia = 0, ib = 0;
  for (int it = 0; it < TK; ++it) {
    bool take_a;
    if (ia >= TK) take_a = false;
    else if (ib >= TK) take_a = true;
    else take_a = (va[ia] >= vb[ib]);  // ties: a's index is smaller
    const float v = take_a ? va[ia] : vb[ib];
    const int j = take_a ? ja[ia] : jb_[ib];
    if (take_a) ++ia; else ++ib;
    E0[(size_t)r * TK + it] = (float)j;
    E1[(size_t)r * TK + it] = (float)r;
    LP[(size_t)r * TK + it] = v;
  }
}

extern "C" void kernel_launch(void* const* d_in, const int* in_sizes, int n_in,
                              void* d_out, int out_size, void* d_ws, size_t ws_size,
                              hipStream_t stream) {
  const float* x = (const float*)d_in[0];
  const float* A = (const float*)d_in[1];
  const float* W = (const float*)d_in[2];
  const float* temp = (const float*)d_in[3];
  const float* q = (const float*)d_in[4];
  float* out = (float*)d_out;

  char* ws = (char*)d_ws;
  float* xw  = (float*)(ws);             //  8,388,608 B
  float* sq  = (float*)(ws + 8388608);   //     32,768 B
  float* hbT = (float*)(ws + 8421376);   //  8,388,608 B  [256][8192]
  float* wsV = (float*)(ws + 16809984);  //  1,048,576 B  [2][8192][16]
  int*   wsJ = (int*)  (ws + 17858560);  //  1,048,576 B

  float* hb = out;  // [N, DE] f32 output region holds h

  hipLaunchKernelGGL((k_gemm<DI, false>), dim3(NN / 32), dim3(512), 0, stream, x, DI, W, xw);
  hipLaunchKernelGGL((k_gemm<NN, true>), dim3(NN / 32), dim3(512), 0, stream, A, NN, xw, hb);
  hipLaunchKernelGGL(k_tr, dim3(NN / 64, DE / 64), dim3(256), 0, stream, hb, hbT);
  hipLaunchKernelGGL(k_sq32, dim3(NN / 256), dim3(256), 0, stream, hb, sq);
  hipLaunchKernelGGL(k_sel, dim3(NN / 32, 2), dim3(512), 0, stream, hb, hbT, sq, q, temp, wsV, wsJ);
  hipLaunchKernelGGL(k_merge, dim3(NN / 256), dim3(256), 0, stream, wsV, wsJ, out);
}

// Round 9
// 2172.583 us; speedup vs baseline: 1.4448x; 1.0648x over previous
//
#include <hip/hip_runtime.h>
#include <math.h>

// DGM edge sampler, N=8192, DIN=512, DEMB=256, K=16.
// Canonical-f32 pipeline (bit-faithful to the np reference): k-ascending FMA
// GEMMs, numpy-pairwise row sums, explicit __f*_rn at every op boundary.
// Round 9: occupancy push under the empirical LDS co-residency limit
// (2 blocks/CU needs <= ~64KB/block; 73KB ran 1/CU in round 8):
//  - k_sel: 38KB LDS (scores overwrite the dead B-chunk in Bs), j-split grid
//    (256,2); per-selector sorted lists dumped to ws; k_merge folds 32 lists.
//  - k_gemm: column-split grid (256,2), 20.6KB LDS.

#define NN 8192
#define DI 512
#define DE 256
#define TK 16

typedef float4 f4;

// ======== K1/K2: C[:, c0:c0+128] = [relu](Amat @ Bmat), col-split ========
// block: 32 rows x 128 cols, 512 threads; thread: 2 rows x 4 cols.
template <int KTOT, bool RELU>
__global__ __launch_bounds__(512) void k_gemm(const float* __restrict__ Amat, int lda,
                                              const float* __restrict__ Bmat,
                                              float* __restrict__ Cout) {
  __shared__ float As[32][36];   // 4.6 KB
  __shared__ float Bs[32][128];  // 16 KB
  const int i0 = blockIdx.x * 32;
  const int c0 = blockIdx.y * 128;
  const int tid = threadIdx.x;
  const int rg = tid >> 5;   // 0..15 -> rows rg*2, rg*2+1
  const int cq = tid & 31;   // cols cq*4..+3
  const int r0 = rg * 2;
  float acc[2][4] = {};
  f4 pa;
  f4 pb[2];
  if (tid < 256) pa = *(const f4*)&Amat[(size_t)(i0 + (tid >> 3)) * lda + (tid & 7) * 4];
#pragma unroll
  for (int w = 0; w < 2; ++w) {
    const int lin = tid + 512 * w;
    pb[w] = *(const f4*)&Bmat[(size_t)(lin >> 5) * DE + c0 + (lin & 31) * 4];
  }

  for (int k0 = 0; k0 < KTOT; k0 += 32) {
    __syncthreads();
    if (tid < 256) *(f4*)&As[tid >> 3][(tid & 7) * 4] = pa;
#pragma unroll
    for (int w = 0; w < 2; ++w) {
      const int lin = tid + 512 * w;
      *(f4*)&Bs[lin >> 5][(lin & 31) * 4] = pb[w];
    }
    if (k0 + 32 < KTOT) {
      if (tid < 256)
        pa = *(const f4*)&Amat[(size_t)(i0 + (tid >> 3)) * lda + k0 + 32 + (tid & 7) * 4];
#pragma unroll
      for (int w = 0; w < 2; ++w) {
        const int lin = tid + 512 * w;
        pb[w] = *(const f4*)&Bmat[(size_t)(k0 + 32 + (lin >> 5)) * DE + c0 + (lin & 31) * 4];
      }
    }
    __syncthreads();
#pragma unroll
    for (int k4 = 0; k4 < 8; ++k4) {
      f4 av[2];
#pragma unroll
      for (int u = 0; u < 2; ++u) av[u] = *(const f4*)&As[r0 + u][k4 * 4];  // broadcast
#pragma unroll
      for (int kk = 0; kk < 4; ++kk) {  // k ascending
        f4 b = *(const f4*)&Bs[k4 * 4 + kk][cq * 4];  // stride-1 b128
        const float* bf = (const float*)&b;
#pragma unroll
        for (int u = 0; u < 2; ++u) {
          const float a = ((const float*)&av[u])[kk];
#pragma unroll
          for (int m = 0; m < 4; ++m) acc[u][m] = __fmaf_rn(a, bf[m], acc[u][m]);
        }
      }
    }
  }
#pragma unroll
  for (int u = 0; u < 2; ++u) {
    const int i = i0 + r0 + u;
    f4 o;
    float* of = (float*)&o;
#pragma unroll
    for (int m = 0; m < 4; ++m) of[m] = RELU ? fmaxf(acc[u][m], 0.0f) : acc[u][m];
    *(f4*)&Cout[(size_t)i * DE + c0 + cq * 4] = o;
  }
}

// ======== K2b: hbT[k][i] = hb[i][k]  (64x64 LDS tiles, pad 65) ========
__global__ __launch_bounds__(256) void k_tr(const float* __restrict__ hb,
                                            float* __restrict__ hbT) {
  __shared__ float t[64][65];
  const int i0 = blockIdx.x * 64;
  const int k0 = blockIdx.y * 64;
  const int tid = threadIdx.x;
#pragma unroll
  for (int l = 0; l < 4; ++l) {
    const int lin = tid + 256 * l;
    const int r = lin >> 4, cqq = lin & 15;
    f4 v = *(const f4*)&hb[(size_t)(i0 + r) * DE + k0 + cqq * 4];
    const float* vf = (const float*)&v;
#pragma unroll
    for (int w = 0; w < 4; ++w) t[r][cqq * 4 + w] = vf[w];
  }
  __syncthreads();
#pragma unroll
  for (int l = 0; l < 4; ++l) {
    const int kk = (tid >> 4) + 16 * l;
    const int iq = tid & 15;
    f4 o;
    float* of = (float*)&o;
#pragma unroll
    for (int w = 0; w < 4; ++w) of[w] = t[iq * 4 + w][kk];
    *(f4*)&hbT[(size_t)(k0 + kk) * NN + i0 + iq * 4] = o;
  }
}

// ======== K3: sq[i] = sum(h_i*h_i), numpy-pairwise structure ========
__global__ __launch_bounds__(256) void k_sq32(const float* __restrict__ hb,
                                              float* __restrict__ sq) {
  const int row = blockIdx.x * 256 + threadIdx.x;
  const float* h = hb + (size_t)row * DE;
  float half[2];
#pragma unroll
  for (int hx = 0; hx < 2; ++hx) {
    float p[8] = {};
    for (int t = 0; t < 16; ++t) {
      f4 v0 = *(const f4*)&h[hx * 128 + t * 8];
      f4 v1 = *(const f4*)&h[hx * 128 + t * 8 + 4];
      const float* v0f = (const float*)&v0;
      const float* v1f = (const float*)&v1;
#pragma unroll
      for (int m = 0; m < 4; ++m) {
        p[m] = __fadd_rn(p[m], __fmul_rn(v0f[m], v0f[m]));
        p[4 + m] = __fadd_rn(p[4 + m], __fmul_rn(v1f[m], v1f[m]));
      }
    }
    const float t01 = __fadd_rn(p[0], p[1]), t23 = __fadd_rn(p[2], p[3]);
    const float t45 = __fadd_rn(p[4], p[5]), t67 = __fadd_rn(p[6], p[7]);
    half[hx] = __fadd_rn(__fadd_rn(t01, t23), __fadd_rn(t45, t67));
  }
  sq[row] = __fadd_rn(half[0], half[1]);
}

// ======== K4: fused f32 scoring + parallel streaming top-16 (j-split) ========
// grid (NN/32, 2): 32 rows x 4096-j half per block, 512 threads, LDS 38KB.
// compute thread: rg=tid>>6 (rows rg*4..+3, A broadcast), cq=tid&63 (4 cols).
// scores OVERWRITE Bs (dead B-chunk) at kc==7 -> no separate sc tile.
// selector thread: sr=tid>>4 row, ss=tid&15; register sorted top-16; lists
// dumped raw to wsV/wsJ (32 lists/row); k_merge does the exact 32-way merge.
__global__ __launch_bounds__(512) void k_sel(const float* __restrict__ hb,
                                             const float* __restrict__ hbT,
                                             const float* __restrict__ sqv,
                                             const float* __restrict__ q,
                                             const float* __restrict__ temp,
                                             float* __restrict__ wsV,
                                             int* __restrict__ wsJ) {
  __shared__ float Has[32][36];  // 4.6 KB, restaged per 32-k chunk
  __shared__ float Bs[32][260];  // 33.3 KB: B-chunk, then scores at kc==7
  const int i0 = blockIdx.x * 32;
  const int jb = blockIdx.y;        // j-half: [jb*4096, jb*4096+4096)
  const int jbase = jb * 4096;
  const int tid = threadIdx.x;
  const int rg = tid >> 6;  // 0..7
  const int cq = tid & 63;  // 0..63
  const int r0 = rg * 4;
  const int sr = tid >> 4;  // selector row 0..31
  const int ss = tid & 15;  // selector sub-index

  const float tt = fminf(fmaxf(temp[0], -5.0f), 5.0f);
  const float C = expf(tt);
  float sqi[4];
#pragma unroll
  for (int u = 0; u < 4; ++u) sqi[u] = sqv[i0 + r0 + u];

  float acc[4][4] = {};
  float lv[16];
  int lj[16];
#pragma unroll
  for (int u = 0; u < TK; ++u) { lv[u] = -3.0e38f; lj[u] = 0x7fffffff; }

  // prefetch chunk 0 (jt=0, kc=0)
  f4 pa;
  f4 pb[4];
  if (tid < 256) pa = *(const f4*)&hb[(size_t)(i0 + (tid >> 3)) * DE + (tid & 7) * 4];
#pragma unroll
  for (int w = 0; w < 4; ++w) {
    const int lin = tid + 512 * w;
    pb[w] = *(const f4*)&hbT[(size_t)(lin >> 6) * NN + jbase + (lin & 63) * 4];
  }

  for (int s = 0; s < 128; ++s) {  // jt = s>>3 (16 tiles), kc = s&7
    __syncthreads();               // Has/Bs free (prev compute+selection done)
    if (tid < 256) *(f4*)&Has[tid >> 3][(tid & 7) * 4] = pa;
#pragma unroll
    for (int w = 0; w < 4; ++w) {
      const int lin = tid + 512 * w;
      *(f4*)&Bs[lin >> 6][(lin & 63) * 4] = pb[w];
    }
    if (s + 1 < 128) {
      const int jt1 = (s + 1) >> 3, kc1 = (s + 1) & 7;
      if (tid < 256)
        pa = *(const f4*)&hb[(size_t)(i0 + (tid >> 3)) * DE + kc1 * 32 + (tid & 7) * 4];
#pragma unroll
      for (int w = 0; w < 4; ++w) {
        const int lin = tid + 512 * w;
        pb[w] = *(const f4*)&hbT[(size_t)(kc1 * 32 + (lin >> 6)) * NN + jbase + jt1 * 256 + (lin & 63) * 4];
      }
    }
    __syncthreads();               // staged tiles ready
#pragma unroll
    for (int k4 = 0; k4 < 8; ++k4) {
      f4 av[4];
#pragma unroll
      for (int u = 0; u < 4; ++u) av[u] = *(const f4*)&Has[r0 + u][k4 * 4];  // broadcast
#pragma unroll
      for (int kk = 0; kk < 4; ++kk) {  // k ascending
        f4 b = *(const f4*)&Bs[k4 * 4 + kk][cq * 4];  // stride-1 b128
        const float* bf = (const float*)&b;
#pragma unroll
        for (int u = 0; u < 4; ++u) {
          const float a = ((const float*)&av[u])[kk];
#pragma unroll
          for (int m = 0; m < 4; ++m) acc[u][m] = __fmaf_rn(a, bf[m], acc[u][m]);
        }
      }
    }
    if ((s & 7) == 7) {
      const int j0s = jbase + (s >> 3) * 256;
      __syncthreads();             // all compute reads of Bs done -> reuse as sc
      // scores (instruction-identical to the round-4 passing formula)
      f4 sqj = *(const f4*)&sqv[j0s + cq * 4];
      const float* sqjf = (const float*)&sqj;
#pragma unroll
      for (int u = 0; u < 4; ++u) {
        const int i = i0 + r0 + u;
        f4 qv = *(const f4*)&q[(size_t)i * NN + j0s + cq * 4];
        const float* qvf = (const float*)&qv;
        f4 sv;
        float* svf = (float*)&sv;
#pragma unroll
        for (int e = 0; e < 4; ++e) {
          const float t1 = __fadd_rn(sqi[u], sqjf[e]);
          float D = __fsub_rn(t1, __fmul_rn(2.0f, acc[u][e]));
          D = fmaxf(D, 0.0f);
          const float lg = __fmul_rn(D, C);
          const float p = __fadd_rn(qvf[e], 1e-8f);
          const float uu = logf(p);
          const float nv = logf(-uu);
          svf[e] = __fsub_rn(nv, lg);
          acc[u][e] = 0.0f;
        }
        *(f4*)&Bs[r0 + u][cq * 4] = sv;   // scores into dead B-chunk
      }
      __syncthreads();             // scores ready
      // selection: ascending j within selector (j = j0s + c*16 + ss)
      for (int c = 0; c < 16; ++c) {
        const float v = Bs[sr][c * 16 + ss];
        if (v > lv[15]) {          // strict: ties keep earlier (smaller) j
          float cv = v;
          int cj = j0s + c * 16 + ss;
#pragma unroll
          for (int u = 0; u < TK; ++u) {
            const bool take = (cv > lv[u]);
            const float nv2 = take ? cv : lv[u];
            const int nj2 = take ? cj : lj[u];
            cv = take ? lv[u] : cv;
            cj = take ? lj[u] : cj;
            lv[u] = nv2;
            lj[u] = nj2;
          }
        }
      }
      // loop-top barrier protects Bs (scores) vs next staging write
    }
  }

  // ---- dump 16-deep sorted list to workspace (no LDS needed) ----
  const size_t base = (((size_t)jb * NN + i0 + sr) * 16 + ss) * (size_t)TK;
#pragma unroll
  for (int u = 0; u < TK; ++u) {
    wsV[base + u] = lv[u];
    wsJ[base + u] = lj[u];
  }
}

// ======== K5: exact 32-way cursor merge per row ========
// Lists sorted desc by value (ties: asc j by construction). Comparator
// (v desc, j asc) across heads reproduces lax.top_k exactly.
__global__ __launch_bounds__(256) void k_merge(const float* __restrict__ wsV,
                                               const int* __restrict__ wsJ,
                                               float* __restrict__ out) {
  const int r = blockIdx.x * 256 + threadIdx.x;
  int cur[32];
#pragma unroll
  for (int l = 0; l < 32; ++l) cur[l] = 0;
  float* E0 = out + (size_t)NN * DE;
  float* E1 = E0 + (size_t)NN * TK;
  float* LP = E1 + (size_t)NN * TK;
  for (int it = 0; it < TK; ++it) {
    float bv = -3.0e38f;
    int bj = 0x7fffffff, bl = 0;
    for (int l = 0; l < 32; ++l) {
      const int c = cur[l];
      if (c < TK) {
        const size_t base = (((size_t)(l >> 4) * NN + r) * 16 + (l & 15)) * (size_t)TK;
        const float v = wsV[base + c];
        const int j = wsJ[base + c];
        if (v > bv || (v == bv && j < bj)) { bv = v; bj = j; bl = l; }
      }
    }
    cur[bl]++;
    E0[(size_t)r * TK + it] = (float)bj;
    E1[(size_t)r * TK + it] = (float)r;
    LP[(size_t)r * TK + it] = bv;
  }
}

extern "C" void kernel_launch(void* const* d_in, const int* in_sizes, int n_in,
                              void* d_out, int out_size, void* d_ws, size_t ws_size,
                              hipStream_t stream) {
  const float* x = (const float*)d_in[0];
  const float* A = (const float*)d_in[1];
  const float* W = (const float*)d_in[2];
  const float* temp = (const float*)d_in[3];
  const float* q = (const float*)d_in[4];
  float* out = (float*)d_out;

  char* ws = (char*)d_ws;
  float* xw  = (float*)(ws);             //  8,388,608 B
  float* sq  = (float*)(ws + 8388608);   //     32,768 B
  float* hbT = (float*)(ws + 8421376);   //  8,388,608 B  [256][8192]
  float* wsV = (float*)(ws + 16809984);  // 16,777,216 B  [2][8192][16][16]
  int*   wsJ = (int*)  (ws + 33587200);  // 16,777,216 B

  float* hb = out;  // [N, DE] f32 output region holds h

  hipLaunchKernelGGL((k_gemm<DI, false>), dim3(NN / 32, 2), dim3(512), 0, stream, x, DI, W, xw);
  hipLaunchKernelGGL((k_gemm<NN, true>), dim3(NN / 32, 2), dim3(512), 0, stream, A, NN, xw, hb);
  hipLaunchKernelGGL(k_tr, dim3(NN / 64, DE / 64), dim3(256), 0, stream, hb, hbT);
  hipLaunchKernelGGL(k_sq32, dim3(NN / 256), dim3(256), 0, stream, hb, sq);
  hipLaunchKernelGGL(k_sel, dim3(NN / 32, 2), dim3(512), 0, stream, hb, hbT, sq, q, temp, wsV, wsJ);
  hipLaunchKernelGGL(k_merge, dim3(NN / 256), dim3(256), 0, stream, wsV, wsJ, out);
}